// Round 10
// baseline (103.976 us; speedup 1.0000x reference)
//
#include <hip/hip_runtime.h>
#include <hip/hip_bf16.h>
#include <math.h>

// Problem constants
#define Hn 256
#define Nn 64
#define Bn 4
#define Ln 2048
#define NC 32      // chunks per sequence

typedef __attribute__((ext_vector_type(8))) short short8;
typedef __attribute__((ext_vector_type(4))) float f32x4;

#define MFMA16 __builtin_amdgcn_mfma_f32_16x16x32_bf16

// AF1: per h, 16 slots x 512 shorts = 8192 shorts (64x64 re/im, bf16-hi only)
#define AF1_STRIDE 8192
// AF2: per h, 24 slots x 512 shorts = 12288 shorts (64x192, bf16-hi only)
#define AF2_STRIDE 12288

__device__ inline short bf16hi(float x) {
    union { __hip_bfloat16 b; unsigned short u; } cv;
    cv.b = __float2bfloat16(x);
    return (short)cv.u;
}
__device__ inline float bf16f(short s) {
    union { __hip_bfloat16 b; unsigned short u; } cv;
    cv.u = (unsigned short)s;
    return __bfloat162float(cv.b);
}

// complex square in place
#define CSQ(r, i) { float _nr = (r)*(r) - (i)*(i); (i) = 2.f*(r)*(i); (r) = _nr; }

// ---------------------------------------------------------------------------
// K0: blocks [0,512): transpose u (B,L,H)->uT (B,H,L), float4 both ways.
//     blocks [512,768): per-h precompute, emitting MFMA A-fragments (bf16-hi):
//       AF1[h]: Apow (re,im) — A1[n][t] = a_n^{63-t}, 64x64
//       AF2[h]: [T | Gre | -Gim] — 64x192
//       apar[h][n] = a_n^64 (complex)
//     Fragment layout (16x16x32 bf16 A-op): lane holds A[m=lane&15][k=quad*8+j]
//     stored [..][mt][kt][lane][j] so k_scan_chunks reads short8 at lane*8.
// ---------------------------------------------------------------------------
__global__ __launch_bounds__(256)
void k_pre(const float* __restrict__ u, float* __restrict__ uT,
           const float* __restrict__ lnr, const float* __restrict__ im,
           const float* __restrict__ Bre, const float* __restrict__ Bim,
           const float* __restrict__ Cre, const float* __restrict__ Cim,
           const float* __restrict__ lstep,
           short* __restrict__ AF1, short* __restrict__ AF2,
           float* __restrict__ apar)
{
    __shared__ float sh[2][64][66];
    __shared__ float cbrL[64];
    __shared__ float kb[128];
    int bid = blockIdx.x;
    int tid = threadIdx.x;

    if (bid < 512) {
        // ---- transpose tile ----
        int b  = bid >> 7;
        int h0 = ((bid >> 5) & 3) << 6;
        int l0 = (bid & 31) << 6;
        int c4 = tid & 15, rr = tid >> 4;
        #pragma unroll
        for (int i = 0; i < 4; ++i) {
            int r = rr + (i << 4);
            float4 v = *(const float4*)&u[((size_t)b * Ln + l0 + r) * Hn + h0 + (c4 << 2)];
            sh[0][r][(c4 << 2) + 0] = v.x;
            sh[0][r][(c4 << 2) + 1] = v.y;
            sh[0][r][(c4 << 2) + 2] = v.z;
            sh[0][r][(c4 << 2) + 3] = v.w;
        }
        __syncthreads();
        #pragma unroll
        for (int i = 0; i < 4; ++i) {
            int hr = (tid >> 4) + (i << 4);
            int lc = tid & 15;
            float4 v;
            v.x = sh[0][(lc << 2) + 0][hr];
            v.y = sh[0][(lc << 2) + 1][hr];
            v.z = sh[0][(lc << 2) + 2][hr];
            v.w = sh[0][(lc << 2) + 3][hr];
            *(float4*)&uT[((size_t)b * Hn + h0 + hr) * Ln + l0 + (lc << 2)] = v;
        }
        return;
    }

    // ---- per-h precompute ----
    int h    = bid - 512;
    int lane = tid & 63;
    int wv   = tid >> 6;
    int kq   = lane >> 4;
    int l15  = lane & 15;
    int mrow = (wv << 4) + l15;

    // per-lane (n = lane) parameters — every wave recomputes (cheap)
    float st  = fminf(fmaxf(expf(lstep[h]), 1e-5f), 1.0f);
    float lam = -expf(lnr[lane]);
    float er  = expf(st * lam);
    float smv = st * im[lane];
    float ar  = er * cosf(smv);
    float ai  = er * sinf(smv);
    float bre = Bre[h * Nn + lane] * st;
    float bim = Bim[h * Nn + lane] * st;
    float crr = Cre[h * Nn + lane];
    float cii = Cim[h * Nn + lane];
    float cbr = crr * bre - cii * bim;
    float cbi = crr * bim + cii * bre;

    // power ladder: a^16, a^32, a^48, a^64
    float a16r = ar, a16i = ai;
    CSQ(a16r, a16i); CSQ(a16r, a16i); CSQ(a16r, a16i); CSQ(a16r, a16i);
    float a32r = a16r, a32i = a16i; CSQ(a32r, a32i);
    float a48r = a32r * a16r - a32i * a16i;
    float a48i = a32r * a16i + a32i * a16r;
    float a64r = a32r, a64i = a32i; CSQ(a64r, a64i);
    if (tid < 64) {
        apar[(h * Nn + lane) * 2]     = a64r;
        apar[(h * Nn + lane) * 2 + 1] = a64i;
    }

    // stage A: Apow[n][t] = a^(63-t); wave wv covers powers 16*wv .. 16*wv+15
    float pr = 1.f, pi = 0.f;
    if (wv == 1) { pr = a16r; pi = a16i; }
    else if (wv == 2) { pr = a32r; pi = a32i; }
    else if (wv == 3) { pr = a48r; pi = a48i; }
    for (int i = 0; i < 16; ++i) {
        int t = 63 - ((wv << 4) + i);
        sh[0][lane][t] = pr;
        sh[1][lane][t] = pi;
        float nr = pr * ar - pi * ai; pi = pr * ai + pi * ar; pr = nr;
    }
    __syncthreads();

    // AF1 fragment stores (bf16-hi only)
    short* A1h = AF1 + (size_t)h * AF1_STRIDE;
    #pragma unroll
    for (int cm = 0; cm < 2; ++cm)
        #pragma unroll
        for (int kt = 0; kt < 2; ++kt) {
            union { short s[8]; short8 v; } uh;
            #pragma unroll
            for (int j = 0; j < 8; ++j)
                uh.s[j] = bf16hi(sh[cm][mrow][kt * 32 + kq * 8 + j]);
            *(short8*)&A1h[((cm * 4 + wv) * 2 + kt) * 512 + lane * 8] = uh.v;
        }
    __syncthreads();

    // stage B: Gre/Gim into sh (G[j][n] = CB * a^(j+1))
    if (tid < 64) {
        cbrL[lane] = cbr;
        float Pr = ar, Pi = ai;
        for (int j = 0; j < 64; ++j) {
            sh[0][j][lane] = cbr * Pr - cbi * Pi;
            sh[1][j][lane] = cbr * Pi + cbi * Pr;
            float nr = Pr * ar - Pi * ai; Pi = Pr * ai + Pi * ar; Pr = nr;
        }
    }
    __syncthreads();
    // Krow -> kb (zero-padded low half): Krow[t] = sum_n Re(CB_n a_n^t)
    if (tid < 64) kb[tid] = 0.f;
    else if (tid < 128) {
        int t2 = tid - 64;
        float s = 0.f;
        if (t2 == 0) { for (int n2 = 0; n2 < 64; ++n2) s += cbrL[n2]; }
        else         { for (int n2 = 0; n2 < 64; ++n2) s += sh[0][t2 - 1][n2]; }
        kb[tid] = s;
    }
    __syncthreads();

    // AF2 fragment stores: A2 = [T | Gre | -Gim], 64x192 (bf16-hi only)
    short* A2h = AF2 + (size_t)h * AF2_STRIDE;
    #pragma unroll
    for (int kt = 0; kt < 6; ++kt) {
        union { short s[8]; short8 v; } uh;
        #pragma unroll
        for (int j = 0; j < 8; ++j) {
            float x;
            if (kt < 2) {
                int kk = kt * 32 + kq * 8 + j;          // m index of T
                x = kb[64 + mrow - kk];                  // T[j][m] = Krow[j-m]
            } else {
                int q2 = kt - 2;
                int nn = (q2 & 1) * 32 + kq * 8 + j;
                x = (q2 >> 1) ? -sh[1][mrow][nn] : sh[0][mrow][nn];
            }
            uh.s[j] = bf16hi(x);
        }
        *(short8*)&A2h[(wv * 6 + kt) * 512 + lane * 8] = uh.v;
    }
}

// ---------------------------------------------------------------------------
// K1 (MFMA scan+chunks). block = (b,h), 4 waves; wave w owns m-tile w.
//  set1: P(64n x 32c) = Apow(64x64) * U(64t x 32c)   [A bf16-hi, U hi/lo]
//  scan: S[c] = a64*S[c-1] + P[c-1] (32 steps, lane = n, waves duplicate,
//        wave w stages bf16 hi/lo S for its c-range into Sb)
//  set2: Y(64j x 32c) = [T|Gre|-Gim](64x192) * [U;Sre;Sim](192x32)
//  epilogue: Y + D*u -> exact GELU -> ypre[b,h,l]
// ---------------------------------------------------------------------------
__global__ __launch_bounds__(256, 4)
void k_scan_chunks(const float* __restrict__ uT, const float* __restrict__ apar,
                   const short* __restrict__ AF1, const short* __restrict__ AF2,
                   const float* __restrict__ D, float* __restrict__ ypre)
{
    __shared__ float P2[64][35][2];        // P (re,im) fp32; aliased as Y later
    __shared__ short Sb[2][2][32][72];     // [split][reim][c][n]

    int bh   = blockIdx.x;
    int h    = bh & (Hn - 1);
    int tid  = threadIdx.x;
    int lane = tid & 63;
    int w    = __builtin_amdgcn_readfirstlane(tid >> 6);
    int l15  = lane & 15;
    int kq   = lane >> 4;

    const float* uRow = uT + (size_t)bh * Ln;
    const short* A1h  = AF1 + (size_t)h * AF1_STRIDE;
    const short* A2h  = AF2 + (size_t)h * AF2_STRIDE;

    // ---- U fragments direct from global (L1), bf16 hi/lo ----
    short8 Uh[2][2], Ul[2][2];             // [kt][ct]
    #pragma unroll
    for (int kt = 0; kt < 2; ++kt)
        #pragma unroll
        for (int ct = 0; ct < 2; ++ct) {
            int c = ct * 16 + l15;
            const float* up = uRow + c * 64 + kt * 32 + kq * 8;
            float4 f0 = *(const float4*)up;
            float4 f1 = *(const float4*)(up + 4);
            float xv[8] = {f0.x, f0.y, f0.z, f0.w, f1.x, f1.y, f1.z, f1.w};
            union { short s[8]; short8 v; } hh, ll;
            #pragma unroll
            for (int j = 0; j < 8; ++j) {
                short hs = bf16hi(xv[j]);
                hh.s[j] = hs;
                ll.s[j] = bf16hi(xv[j] - bf16f(hs));
            }
            Uh[kt][ct] = hh.v;
            Ul[kt][ct] = ll.v;
        }

    // ---- set 1: P = Apow * U ----
    f32x4 Pre_acc[2] = {{0.f,0.f,0.f,0.f},{0.f,0.f,0.f,0.f}};
    f32x4 Pim_acc[2] = {{0.f,0.f,0.f,0.f},{0.f,0.f,0.f,0.f}};
    #pragma unroll
    for (int kt = 0; kt < 2; ++kt) {
        short8 a_re = *(const short8*)&A1h[((0 * 4 + w) * 2 + kt) * 512 + lane * 8];
        short8 a_im = *(const short8*)&A1h[((1 * 4 + w) * 2 + kt) * 512 + lane * 8];
        #pragma unroll
        for (int ct = 0; ct < 2; ++ct) {
            Pre_acc[ct] = MFMA16(a_re, Uh[kt][ct], Pre_acc[ct], 0, 0, 0);
            Pre_acc[ct] = MFMA16(a_re, Ul[kt][ct], Pre_acc[ct], 0, 0, 0);
            Pim_acc[ct] = MFMA16(a_im, Uh[kt][ct], Pim_acc[ct], 0, 0, 0);
            Pim_acc[ct] = MFMA16(a_im, Ul[kt][ct], Pim_acc[ct], 0, 0, 0);
        }
    }
    // P -> LDS (C/D layout: col = lane&15, row = quad*4 + reg)
    #pragma unroll
    for (int ct = 0; ct < 2; ++ct)
        #pragma unroll
        for (int r = 0; r < 4; ++r) {
            int n = (w << 4) + kq * 4 + r;
            int c = ct * 16 + l15;
            *(float2*)&P2[n][c][0] = make_float2(Pre_acc[ct][r], Pim_acc[ct][r]);
        }
    __syncthreads();

    // ---- scan (lane = n); every wave duplicates, wave w stages its c-range ----
    {
        int n = lane;
        float a64r = apar[(h * Nn + n) * 2];
        float a64i = apar[(h * Nn + n) * 2 + 1];
        float sr = 0.f, si = 0.f;
        for (int c = 0; c < NC; ++c) {
            if ((c >> 3) == w) {
                short hr = bf16hi(sr); short lr = bf16hi(sr - bf16f(hr));
                short hi2 = bf16hi(si); short li = bf16hi(si - bf16f(hi2));
                Sb[0][0][c][n] = hr;  Sb[1][0][c][n] = lr;
                Sb[0][1][c][n] = hi2; Sb[1][1][c][n] = li;
            }
            float2 pv = *(float2*)&P2[n][c][0];
            float nsr = fmaf(a64r, sr, fmaf(-a64i, si, pv.x));
            float nsi = fmaf(a64i, sr, fmaf(a64r, si, pv.y));
            sr = nsr; si = nsi;
        }
    }
    __syncthreads();

    // ---- set 2: Y = [T|Gre|-Gim] * [U;Sre;Sim] ----
    f32x4 Yacc[2] = {{0.f,0.f,0.f,0.f},{0.f,0.f,0.f,0.f}};
    #pragma unroll
    for (int kt = 0; kt < 6; ++kt) {
        short8 a_h = *(const short8*)&A2h[(w * 6 + kt) * 512 + lane * 8];
        #pragma unroll
        for (int ct = 0; ct < 2; ++ct) {
            short8 bhf, blf;
            if (kt < 2) { bhf = Uh[kt][ct]; blf = Ul[kt][ct]; }
            else {
                int q2 = kt - 2, reim = q2 >> 1;
                int nb = (q2 & 1) * 32 + kq * 8;
                int c  = ct * 16 + l15;
                bhf = *(const short8*)&Sb[0][reim][c][nb];
                blf = *(const short8*)&Sb[1][reim][c][nb];
            }
            Yacc[ct] = MFMA16(a_h, bhf, Yacc[ct], 0, 0, 0);
            Yacc[ct] = MFMA16(a_h, blf, Yacc[ct], 0, 0, 0);
        }
    }
    // Y -> LDS (reuse P2 region, stride 70 floats)
    float* Yl = (float*)P2;
    #pragma unroll
    for (int ct = 0; ct < 2; ++ct)
        #pragma unroll
        for (int r = 0; r < 4; ++r) {
            int j = (w << 4) + kq * 4 + r;
            int c = ct * 16 + l15;
            Yl[j * 70 + c] = Yacc[ct][r];
        }
    __syncthreads();

    // ---- epilogue: +D*u, exact GELU, coalesced store ----
    float Dh = D[h];
    #pragma unroll
    for (int i = 0; i < 8; ++i) {
        int c = (w << 3) + i;
        float y  = Yl[lane * 70 + c];
        float uv = uRow[c * 64 + lane];
        float yv = fmaf(Dh, uv, y);
        float g  = 0.5f * yv * (1.f + erff(yv * 0.70710678118654752f));
        ypre[(size_t)bh * Ln + c * 64 + lane] = g;
    }
}

// ---------------------------------------------------------------------------
// K2: LayerNorm over H; 8-l tiles for occupancy (1024 blocks, 8.4 KB LDS).
// grid: (256 ltiles, 4 b) x 256 threads.
// ---------------------------------------------------------------------------
__global__ __launch_bounds__(256)
void k_ln(const float* __restrict__ ypre, const float* __restrict__ gamma,
          const float* __restrict__ beta, float* __restrict__ out)
{
    __shared__ float tile[8][264];
    int b  = blockIdx.y;
    int l0 = blockIdx.x << 3;
    int t  = threadIdx.x;
    int wv = t >> 6, lane = t & 63;

    // stage 8 l x 256 h: thread t = h, two float4 along l
    {
        int hh = t;
        const float* yp = &ypre[((size_t)b * Hn + hh) * Ln + l0];
        float4 v0 = *(const float4*)yp;
        float4 v1 = *(const float4*)(yp + 4);
        tile[0][hh] = v0.x; tile[1][hh] = v0.y; tile[2][hh] = v0.z; tile[3][hh] = v0.w;
        tile[4][hh] = v1.x; tile[5][hh] = v1.y; tile[6][hh] = v1.z; tile[7][hh] = v1.w;
    }
    __syncthreads();

    float4 g4 = *(const float4*)&gamma[lane << 2];
    float4 b4 = *(const float4*)&beta[lane << 2];
    #pragma unroll
    for (int s = 0; s < 2; ++s) {
        int l = (wv << 1) | s;
        float4 v = *(const float4*)&tile[l][lane << 2];
        float sum = (v.x + v.y) + (v.z + v.w);
        float sq  = fmaf(v.x, v.x, fmaf(v.y, v.y, fmaf(v.z, v.z, v.w * v.w)));
        #pragma unroll
        for (int off = 32; off; off >>= 1) {
            sum += __shfl_xor(sum, off);
            sq  += __shfl_xor(sq, off);
        }
        float mean = sum * (1.f / 256.f);
        float var  = sq * (1.f / 256.f) - mean * mean;
        float rs   = rsqrtf(var + 1e-5f);
        float4 o;
        o.x = (v.x - mean) * rs * g4.x + b4.x;
        o.y = (v.y - mean) * rs * g4.y + b4.y;
        o.z = (v.z - mean) * rs * g4.z + b4.z;
        o.w = (v.w - mean) * rs * g4.w + b4.w;
        *(float4*)&out[((size_t)b * Ln + l0 + l) * Hn + (lane << 2)] = o;
    }
}

// ---------------------------------------------------------------------------
extern "C" void kernel_launch(void* const* d_in, const int* in_sizes, int n_in,
                              void* d_out, int out_size, void* d_ws, size_t ws_size,
                              hipStream_t stream)
{
    const float* u     = (const float*)d_in[0];
    const float* lnr   = (const float*)d_in[1];
    const float* im    = (const float*)d_in[2];
    const float* Bre   = (const float*)d_in[3];
    const float* Bim   = (const float*)d_in[4];
    const float* Cre   = (const float*)d_in[5];
    const float* Cim   = (const float*)d_in[6];
    const float* Dp    = (const float*)d_in[7];
    const float* lstep = (const float*)d_in[8];
    const float* gam   = (const float*)d_in[9];
    const float* bet   = (const float*)d_in[10];
    float* out = (float*)d_out;

    // workspace carve
    float* ws   = (float*)d_ws;
    float* uT   = ws;                                   // 2,097,152 f
    float* apar = uT + (size_t)Bn * Hn * Ln;            //    32,768 f
    float* ypre = apar + (size_t)Hn * Nn * 2;           // 2,097,152 f
    short* AF1  = (short*)(ypre + (size_t)Bn * Hn * Ln);// Hn*8192 sh (16B-aligned)
    short* AF2  = AF1 + (size_t)Hn * AF1_STRIDE;        // Hn*12288 sh

    k_pre<<<768, 256, 0, stream>>>(u, uT, lnr, im, Bre, Bim, Cre, Cim, lstep, AF1, AF2, apar);
    k_scan_chunks<<<Bn * Hn, 256, 0, stream>>>(uT, apar, AF1, AF2, Dp, ypre);
    k_ln<<<dim3(Ln / 8, Bn), 256, 0, stream>>>(ypre, gam, bet, out);
}